// Round 8
// baseline (697.078 us; speedup 1.0000x reference)
//
#include <hip/hip_runtime.h>

typedef __attribute__((ext_vector_type(8))) __bf16   bf16x8;
typedef __attribute__((ext_vector_type(4))) __bf16   bf16x4;
typedef __attribute__((ext_vector_type(8))) _Float16 halfx8;
typedef __attribute__((ext_vector_type(4))) float    floatx4;
typedef __attribute__((ext_vector_type(4))) int      intx4;

#define S_  1024
#define D_  1024
#define H_  16
#define DK_ 64
#define B_  4
#define M_  4096  // B*S

// direct global->LDS DMA, 16B per lane. lds dest must be wave-uniform base
// (HW adds lane*16); global src is per-lane.
__device__ __forceinline__ void gload_lds16(const void* g, void* l) {
  __builtin_amdgcn_global_load_lds(
      (const __attribute__((address_space(1))) unsigned int*)g,
      (__attribute__((address_space(3))) unsigned int*)l, 16, 0, 0);
}

// ---------------- mask dtype probe: int32 0/1 has zero high bytes ----------------
__global__ __launch_bounds__(256) void mask_probe(const unsigned char* __restrict__ m,
                                                  int* __restrict__ flag)
{
  __shared__ unsigned sacc[256];
  const int t = threadIdx.x;
  unsigned acc = 0;
  for (int i = t; i < 4096; i += 256)
    if (i & 3) acc |= m[i];
  sacc[t] = acc;
  __syncthreads();
  if (t == 0) {
    unsigned tot = 0;
    for (int i = 0; i < 256; ++i) tot |= sacc[i];
    flag[0] = tot ? 1 : 0;  // 1 => bytes (bool), 0 => int32
  }
}

// ---------------- fused prologue: cvt, weight transpose, mask bit-pack ----------
// blocks [0,6144): cvt qkv->bf16; [6144,7168): transpose_w;
// [7168,11264): pack mask -> PM[(bh*16+kt)*1024 + s] u64 (bit col = mask!=0)
__global__ __launch_bounds__(256) void prep(
    const float* __restrict__ q, const float* __restrict__ k,
    const float* __restrict__ v, __bf16* __restrict__ X,
    const float* __restrict__ W0, const float* __restrict__ W1,
    const float* __restrict__ W2, const float* __restrict__ W3,
    __bf16* __restrict__ WT, const unsigned char* __restrict__ m,
    const int* __restrict__ flag, unsigned long long* __restrict__ PM)
{
  __shared__ __align__(16) unsigned char shb[9216];
  const int bid = blockIdx.x;
  const int t = threadIdx.x;
  if (bid < 6144) {
    const int z = bid >> 11;           // /2048
    const int bx = bid & 2047;
    const float* src = (z == 0) ? q : (z == 1) ? k : v;
    __bf16* dst = X + (size_t)z * 4194304;
    const size_t idx = ((size_t)bx * 256 + t) * 8;
    floatx4 a = *(const floatx4*)(src + idx);
    floatx4 b = *(const floatx4*)(src + idx + 4);
    bf16x8 o;
#pragma unroll
    for (int j = 0; j < 4; ++j) { o[j] = (__bf16)a[j]; o[4 + j] = (__bf16)b[j]; }
    *(bf16x8*)(dst + idx) = o;
  } else if (bid < 7168) {
    const int g = bid - 6144;
    const int z = g >> 8, yy = (g >> 4) & 15, xx = g & 15;
    const float* W = (z == 0) ? W0 : (z == 1) ? W1 : (z == 2) ? W2 : W3;
    __bf16* O = WT + (size_t)z * (D_ * (size_t)D_);
    __bf16* T = (__bf16*)shb;          // 64*72 bf16 = 9216 B
    const int r0 = yy * 64, c0 = xx * 64;
#pragma unroll
    for (int it = 0; it < 4; ++it) {
      int idx = t * 4 + it * 1024;
      int r = idx >> 6, c = idx & 63;  // c multiple of 4
      floatx4 a = *(const floatx4*)(W + (size_t)(r0 + r) * D_ + c0 + c);
      bf16x4 o;
#pragma unroll
      for (int j = 0; j < 4; ++j) o[j] = (__bf16)a[j];
      *(bf16x4*)(&T[r * 72 + c]) = o;
    }
    __syncthreads();
#pragma unroll
    for (int it = 0; it < 2; ++it) {
      int idx = t * 8 + it * 2048;
      int orow = idx >> 6, oc = idx & 63;  // oc multiple of 8
      bf16x8 vv;
#pragma unroll
      for (int j = 0; j < 8; ++j) vv[j] = T[(oc + j) * 72 + orow];
      *(bf16x8*)(O + (size_t)(c0 + orow) * D_ + (r0 + oc)) = vv;
    }
  } else {
    // mask bit-pack: one thread per (bh, kt, s) u64
    const int pid = (bid - 7168) * 256 + t;     // [0, 1048576)
    const int s   = pid & 1023;
    const int ktq = (pid >> 10) & 15;
    const int bhp = pid >> 14;
    unsigned long long bits = 0;
    if (*flag) {  // byte mask
      const unsigned char* mp = m + (size_t)bhp * 1048576 + (size_t)s * 1024 + ktq * 64;
#pragma unroll
      for (int i = 0; i < 4; ++i) {
        intx4 vv = *(const intx4*)(mp + i * 16);
#pragma unroll
        for (int j = 0; j < 4; ++j) {
          unsigned x = (unsigned)vv[j];
          const int bb = i * 16 + j * 4;
          bits |= (unsigned long long)((x & 0x000000ffu) ? 1u : 0u) << (bb + 0);
          bits |= (unsigned long long)((x & 0x0000ff00u) ? 1u : 0u) << (bb + 1);
          bits |= (unsigned long long)((x & 0x00ff0000u) ? 1u : 0u) << (bb + 2);
          bits |= (unsigned long long)((x & 0xff000000u) ? 1u : 0u) << (bb + 3);
        }
      }
    } else {      // int32 mask
      const int* mi = (const int*)m + (size_t)bhp * 1048576 + (size_t)s * 1024 + ktq * 64;
#pragma unroll
      for (int i = 0; i < 16; ++i) {
        intx4 vv = *(const intx4*)(mi + i * 4);
#pragma unroll
        for (int j = 0; j < 4; ++j)
          bits |= (unsigned long long)(vv[j] ? 1u : 0u) << (i * 4 + j);
      }
    }
    PM[pid] = bits;
  }
}

// ---------------- 128x128-tile GEMM body: C = X[M,1024] @ W + bias ----------------
// m97 structure: linear LDS [128][64] + global_load_lds width 16.
// MODE: 0 fp32 out; 1 fp16 Q*0.125 [b,h,s,dk]; 2 fp16 K; 3 bf16 Vt [b,h,dk,s].
template <int MODE>
__device__ __forceinline__ void gemm_body(
    const __bf16* __restrict__ X, const __bf16* __restrict__ WT,
    const float* __restrict__ bias, void* __restrict__ outp, __bf16* sh,
    const int m0, const int n0)
{
  __bf16* As = sh;             // [128][64] linear
  __bf16* Bs = sh + 128 * 64;  // [128][64] linear
  const int t = threadIdx.x;
  const int w = t >> 6, lane = t & 63, quad = lane >> 4, cl = lane & 15;
  const int wm = w >> 1, wn = w & 1;
  const int srow = lane >> 3, scol = (lane & 7) * 8;  // lane's slot within an 8x64 chunk

  floatx4 acc[4][4];
#pragma unroll
  for (int i = 0; i < 4; ++i)
#pragma unroll
    for (int j = 0; j < 4; ++j) acc[i][j] = (floatx4){0.f, 0.f, 0.f, 0.f};

  for (int kt = 0; kt < 16; ++kt) {
    const int k0 = kt * 64;
    __syncthreads();
#pragma unroll
    for (int it = 0; it < 4; ++it) {
      const int ch = it * 4 + w;  // chunk: rows [ch*8, ch*8+8) of the 128-row tile
      gload_lds16(X  + (size_t)(m0 + ch * 8 + srow) * D_ + k0 + scol, As + ch * 512);
      gload_lds16(WT + (size_t)(n0 + ch * 8 + srow) * D_ + k0 + scol, Bs + ch * 512);
    }
    __syncthreads();  // drains vmcnt -> DMA complete
#pragma unroll
    for (int ks = 0; ks < 2; ++ks) {
      bf16x8 a[4], b[4];
#pragma unroll
      for (int mt = 0; mt < 4; ++mt)
        a[mt] = *(const bf16x8*)(&As[(wm * 64 + mt * 16 + cl) * 64 + ks * 32 + quad * 8]);
#pragma unroll
      for (int nt = 0; nt < 4; ++nt)
        b[nt] = *(const bf16x8*)(&Bs[(wn * 64 + nt * 16 + cl) * 64 + ks * 32 + quad * 8]);
#pragma unroll
      for (int mt = 0; mt < 4; ++mt)
#pragma unroll
        for (int nt = 0; nt < 4; ++nt)
          acc[mt][nt] = __builtin_amdgcn_mfma_f32_16x16x32_bf16(a[mt], b[nt], acc[mt][nt], 0, 0, 0);
    }
  }

  if (MODE <= 2) {
#pragma unroll
    for (int mt = 0; mt < 4; ++mt)
#pragma unroll
      for (int nt = 0; nt < 4; ++nt) {
        const int nl = n0 + wn * 64 + nt * 16 + cl;
        const float bv = bias[nl];
#pragma unroll
        for (int r = 0; r < 4; ++r) {
          const int ml = m0 + wm * 64 + mt * 16 + quad * 4 + r;
          float v = acc[mt][nt][r] + bv;
          if (MODE == 0) {
            ((float*)outp)[(size_t)ml * D_ + nl] = v;
          } else {
            if (MODE == 1) v *= 0.125f;
            const int bb = ml >> 10, ss = ml & 1023, hh = nl >> 6, dd = nl & 63;
            ((_Float16*)outp)[(size_t)((bb * H_ + hh) * S_ + ss) * DK_ + dd] = (_Float16)v;
          }
        }
      }
  } else {
    // V: transpose the wave's 64x64 quadrant via LDS, write coalesced rows of Vt
    __syncthreads();  // all waves done reading As/Bs
    __bf16* T = sh + w * (64 * 72);  // 4 waves x 4608 els = 18432 els total
    const int hbase = n0 + wn * 64;  // 64-aligned -> single head
#pragma unroll
    for (int mt = 0; mt < 4; ++mt)
#pragma unroll
      for (int nt = 0; nt < 4; ++nt) {
        const int nl = hbase + nt * 16 + cl;
        const float bv = bias[nl];
        const int dk = nt * 16 + cl;
#pragma unroll
        for (int r = 0; r < 4; ++r) {
          const int sl = mt * 16 + quad * 4 + r;
          T[dk * 72 + sl] = (__bf16)(acc[mt][nt][r] + bv);
        }
      }
    __syncthreads();
    const int bb = m0 >> 10;
    const int hh = hbase >> 6;
    __bf16* out = (__bf16*)outp;
#pragma unroll
    for (int i = 0; i < 8; ++i) {
      int idx = lane * 8 + i * 512;
      int dk = idx >> 6, sl = idx & 63;  // sl multiple of 8
      bf16x8 v = *(const bf16x8*)(&T[dk * 72 + sl]);
      int sg = (m0 & 1023) + wm * 64 + sl;
      *(bf16x8*)(out + (size_t)((bb * H_ + hh) * DK_ + dk) * S_ + sg) = v;
    }
  }
}

// fused QKV projection: gridDim.z selects which of the three GEMMs
__global__ __launch_bounds__(256) void gemm_qkv(
    const __bf16* __restrict__ Xbf, const __bf16* __restrict__ wt,
    const float* __restrict__ bq, const float* __restrict__ bk,
    const float* __restrict__ bv,
    void* __restrict__ Qo, void* __restrict__ Ko, void* __restrict__ Vto)
{
  __shared__ __bf16 sh[18432];
  const int z = blockIdx.z;
  const int m0 = blockIdx.x * 128, n0 = blockIdx.y * 128;
  if (z == 0)      gemm_body<1>(Xbf,               wt,               bq, Qo,  sh, m0, n0);
  else if (z == 1) gemm_body<2>(Xbf + 4194304,     wt + 1048576,     bk, Ko,  sh, m0, n0);
  else             gemm_body<3>(Xbf + 2 * 4194304, wt + 2 * 1048576, bv, Vto, sh, m0, n0);
}

__global__ __launch_bounds__(256) void gemm_out(
    const __bf16* __restrict__ X, const __bf16* __restrict__ WT,
    const float* __restrict__ bias, float* __restrict__ outp)
{
  __shared__ __bf16 sh[18432];
  gemm_body<0>(X, WT, bias, (void*)outp, sh, blockIdx.x * 128, blockIdx.y * 128);
}

// ---------------- attention: LDS-resident P, 8 waves, 2-deep prefetch ----------
// one wg (8 waves, 512 thr) per (bh, 64-row q-tile). Wave (wr=w&3, wh=w>>2):
// rows wr*16..+16, k-column half wh of each 64-col K tile; PVs its own P half.
// Mask comes pre-bit-packed (PM, 512 B/tile). Loads run 2 tiles ahead (A/B
// register sets, unroll-by-2) so HBM latency hides under two compute phases.
__global__ __launch_bounds__(512, 1) void attn_kernel(
    const _Float16* __restrict__ Q, const _Float16* __restrict__ K,
    const __bf16* __restrict__ Vt, const unsigned long long* __restrict__ PM,
    float* __restrict__ attnW, __bf16* __restrict__ AO)
{
  // LDS map (bytes):
  //   [0,131328)        P  bf16[64][1026] (row stride 2052 B = 513 words == 1 mod 32)
  //                     (first 9216 B double as Qs f16[64][72] during staging)
  //   [131328,140544)   Ks  f16[64][72]     (reused as fp32 exchange after sweep)
  //   [140544,149760)   Vts bf16[64][72]    (exchange spills into here too)
  //   [149760,150272)   Ms  u64[64] bit mask tile
  //   [150272,150528)   rls f32[64] per-row 1/l
  //   [150528,150784)   S1  f32[64] partial row sums from wh=1
  __shared__ __align__(16) unsigned char smem[150784];
  __bf16*        P   = (__bf16*)smem;
  _Float16*      Qs  = (_Float16*)smem;
  _Float16*      Ks  = (_Float16*)(smem + 131328);
  __bf16*        Vts = (__bf16*)(smem + 140544);
  unsigned long long* Ms = (unsigned long long*)(smem + 149760);
  float*         rls = (float*)(smem + 150272);
  float*         S1  = (float*)(smem + 150528);

  const int t = threadIdx.x;
  const int w = t >> 6, lane = t & 63, quad = lane >> 4, cl = lane & 15;
  const int wr = w & 3, wh = w >> 2;
  // XCD-aware bijective swizzle (1024 wgs = 8 XCD x 128): each XCD gets whole bh's
  const int o = blockIdx.x + blockIdx.y * 16;
  const int f = (o & 7) * 128 + (o >> 3);
  const int q0 = (f & 15) * 64;
  const int bh = f >> 4;            // b*16+h

  { // stage Q tile (contiguous 64x64 fp16) into the P region; 1 vec op/thread
    const _Float16* g = Q + (size_t)(bh * S_ + q0) * DK_;
    const int idx = t * 8;
    *(halfx8*)(&Qs[(idx >> 6) * 72 + (idx & 63)]) = *(const halfx8*)(g + idx);
  }

  const _Float16* Kbase  = K  + (size_t)bh * S_ * DK_;
  const __bf16*   Vbase  = Vt + (size_t)bh * DK_ * S_;
  const unsigned long long* PMbase = PM + ((size_t)bh * 16) * 1024 + q0;

  // two register sets for 2-deep prefetch (named, no dynamic indexing)
  halfx8 kA, kB;
  bf16x8 vA, vB;
  unsigned long long mA = 0, mB = 0;

#define LOAD_TILE(KR, VR, MR, KT)                                                  \
  {                                                                                \
    const int k0_ = (KT) * 64;                                                     \
    KR = *(const halfx8*)(Kbase + (size_t)k0_ * DK_ + t * 8);                      \
    VR = *(const bf16x8*)(Vbase + (size_t)(t >> 3) * S_ + k0_ + (t & 7) * 8);      \
    if (t < 64) MR = PMbase[(size_t)(KT) * 1024 + t];                              \
  }

#define STAGE_TILE(KR, VR, MR)                                                     \
  {                                                                                \
    *(halfx8*)(&Ks[(t >> 3) * 72 + (t & 7) * 8]) = KR;                             \
    *(bf16x8*)(&Vts[(t >> 3) * 72 + (t & 7) * 8]) = VR;                            \
    if (t < 64) Ms[t] = MR;                                                        \
  }

#define COMPUTE_TILE(KT)                                                           \
  {                                                                                \
    const int k0 = (KT) * 64;                                                      \
    unsigned long long mrow[4];                                                    \
    _Pragma("unroll")                                                              \
    for (int r = 0; r < 4; ++r) mrow[r] = Ms[wr * 16 + quad * 4 + r];              \
    _Pragma("unroll")                                                              \
    for (int ntl = 0; ntl < 2; ++ntl) {                                            \
      const int nt = wh * 2 + ntl;                                                 \
      floatx4 s = (floatx4){0.f, 0.f, 0.f, 0.f};                                   \
      halfx8 b0 = *(const halfx8*)(&Ks[(nt * 16 + cl) * 72 + quad * 8]);           \
      halfx8 b1 = *(const halfx8*)(&Ks[(nt * 16 + cl) * 72 + 32 + quad * 8]);      \
      __builtin_amdgcn_s_setprio(1);                                               \
      s = __builtin_amdgcn_mfma_f32_16x16x32_f16(a0, b0, s, 0, 0, 0);              \
      s = __builtin_amdgcn_mfma_f32_16x16x32_f16(a1, b1, s, 0, 0, 0);              \
      __builtin_amdgcn_s_setprio(0);                                               \
      _Pragma("unroll")                                                            \
      for (int r = 0; r < 4; ++r) {                                                \
        const int mk = (int)((mrow[r] >> (nt * 16 + cl)) & 1ull);                  \
        float sv = s[r];                                                           \
        sv = (sv < 25.f) ? sv : 25.f;                                              \
        float p = mk ? 0.0f : __expf(sv);                                          \
        __bf16 pb = (__bf16)p;                                                     \
        lacc[r] += (float)pb;                                                      \
        Pw[(quad * 4 + r) * 1026 + k0 + nt * 16 + cl] = pb;                        \
      }                                                                            \
    }                                                                              \
    __builtin_amdgcn_s_setprio(1);                                                 \
    {                                                                              \
      bf16x8 a = *(const bf16x8*)(&Pw[cl * 1026 + k0 + wh * 32 + quad * 8]);       \
      _Pragma("unroll")                                                            \
      for (int nt2 = 0; nt2 < 4; ++nt2) {                                          \
        bf16x8 b = *(const bf16x8*)(&Vts[(nt2 * 16 + cl) * 72 + wh * 32 + quad * 8]); \
        acc_o[nt2] = __builtin_amdgcn_mfma_f32_16x16x32_bf16(a, b, acc_o[nt2], 0, 0, 0); \
      }                                                                            \
    }                                                                              \
    __builtin_amdgcn_s_setprio(0);                                                 \
  }

  LOAD_TILE(kA, vA, mA, 0);
  LOAD_TILE(kB, vB, mB, 1);
  __syncthreads();
  // hoist Q fragments for the whole kernel (Qs region is overwritten by P later)
  const halfx8 a0 = *(const halfx8*)(&Qs[(wr * 16 + cl) * 72 + quad * 8]);
  const halfx8 a1 = *(const halfx8*)(&Qs[(wr * 16 + cl) * 72 + 32 + quad * 8]);

  float lacc[4] = {0.f, 0.f, 0.f, 0.f};
  floatx4 acc_o[4];
#pragma unroll
  for (int i = 0; i < 4; ++i) acc_o[i] = (floatx4){0.f, 0.f, 0.f, 0.f};
  __bf16* Pw = P + (size_t)(wr * 16) * 1026;  // this wave-pair's 16 P rows

  for (int kt2 = 0; kt2 < 8; ++kt2) {
    const int kt = kt2 * 2;
    // ---- phase A: tile kt ----
    __syncthreads();            // prev compute done (and Q hoist, first iter)
    STAGE_TILE(kA, vA, mA);
    __syncthreads();            // staging visible
    if (kt2 < 7) LOAD_TILE(kA, vA, mA, kt + 2);
    COMPUTE_TILE(kt);
    // ---- phase B: tile kt+1 ----
    __syncthreads();
    STAGE_TILE(kB, vB, mB);
    __syncthreads();
    if (kt2 < 7) LOAD_TILE(kB, vB, mB, kt + 3);
    COMPUTE_TILE(kt + 1);
  }
#undef LOAD_TILE
#undef STAGE_TILE
#undef COMPUTE_TILE

  // ---- combine wave-pair partials; compute rl; write AO ----
  __syncthreads();  // sweep done; Ks/Vts dead -> reuse as fp32 exchange
  float* Xo = (float*)(smem + 131328);  // 4 waves x 64 lanes x 16 f = 16 KB
  if (wh == 1) {
#pragma unroll
    for (int nt2 = 0; nt2 < 4; ++nt2)
#pragma unroll
      for (int j = 0; j < 4; ++j)
        Xo[(wr * 64 + lane) * 16 + nt2 * 4 + j] = acc_o[nt2][j];
#pragma unroll
    for (int r = 0; r < 4; ++r) {  // reduce own half's row sums, stash in S1
      float v = lacc[r];
      v += __shfl_xor(v, 1); v += __shfl_xor(v, 2);
      v += __shfl_xor(v, 4); v += __shfl_xor(v, 8);
      if (cl == 0) S1[wr * 16 + quad * 4 + r] = v;
    }
  }
  __syncthreads();
  if (wh == 0) {
    const int bb = bh >> 4, hh = bh & 15;
#pragma unroll
    for (int nt2 = 0; nt2 < 4; ++nt2)
#pragma unroll
      for (int j = 0; j < 4; ++j)
        acc_o[nt2][j] += Xo[(wr * 64 + lane) * 16 + nt2 * 4 + j];
#pragma unroll
    for (int r = 0; r < 4; ++r) {
      float v = lacc[r];
      v += __shfl_xor(v, 1); v += __shfl_xor(v, 2);
      v += __shfl_xor(v, 4); v += __shfl_xor(v, 8);
      v += S1[wr * 16 + quad * 4 + r];
      const int rowg = q0 + wr * 16 + quad * 4 + r;
      const float rl = (v > 0.f) ? 1.0f / v : 0.f;  // guard fully-masked row
      if (cl == 0) rls[wr * 16 + quad * 4 + r] = rl;
#pragma unroll
      for (int nt2 = 0; nt2 < 4; ++nt2) {
        float o2 = acc_o[nt2][r] * rl;
        AO[(size_t)(bb * S_ + rowg) * D_ + hh * DK_ + nt2 * 16 + cl] = (__bf16)o2;
      }
    }
  }
  __syncthreads();  // rls ready; all P writes long since visible

  // ---- normalize phase: 8 waves stream the 64 LDS P rows as fp32 to attnW ----
#pragma unroll
  for (int rr = 0; rr < 8; ++rr) {
    const int row = w * 8 + rr;
    const float rlv = rls[row];
    float* g = attnW + ((size_t)(bh * S_) + q0 + row) * S_;
    const __bf16* prow = &P[(size_t)row * 1026];
#pragma unroll
    for (int i = 0; i < 4; ++i) {
      const int c = lane * 4 + i * 256;
      bf16x4 pv = *(const bf16x4*)(prow + c);
      floatx4 ov;
#pragma unroll
      for (int j = 0; j < 4; ++j) ov[j] = (float)pv[j] * rlv;
      *(floatx4*)(g + c) = ov;
    }
  }
}

extern "C" void kernel_launch(void* const* d_in, const int* in_sizes, int n_in,
                              void* d_out, int out_size, void* d_ws, size_t ws_size,
                              hipStream_t stream)
{
  (void)in_sizes; (void)n_in; (void)out_size; (void)ws_size;
  const float* query = (const float*)d_in[0];
  const float* key   = (const float*)d_in[1];
  const float* value = (const float*)d_in[2];
  const unsigned char* mask = (const unsigned char*)d_in[3];
  const float* Wq = (const float*)d_in[4];
  const float* bq = (const float*)d_in[5];
  const float* Wk = (const float*)d_in[6];
  const float* bk = (const float*)d_in[7];
  const float* Wv = (const float*)d_in[8];
  const float* bv = (const float*)d_in[9];
  const float* Wo = (const float*)d_in[10];
  const float* bo = (const float*)d_in[11];

  __bf16* ws = (__bf16*)d_ws;                       // element offsets in bf16 units
  __bf16*   wt   = ws;                               // 4 x 1M bf16   ( 8 MB)
  _Float16* Qws  = (_Float16*)(ws + 4  * 1048576);   // fp16 [B,H,S,DK]
  _Float16* Kws  = (_Float16*)(ws + 8  * 1048576);   // fp16 [B,H,S,DK]
  __bf16*   Vtws = ws + 12 * 1048576;                // bf16 [B,H,DK,S]
  __bf16*   AOws = ws + 16 * 1048576;                // bf16 [B,S,D]
  __bf16*   Xbf  = ws + 20 * 1048576;                // bf16 q,k,v    (3 x 8 MB)
  int*      mfl  = (int*)(ws + 32 * 1048576 + 131072);
  unsigned long long* PM = (unsigned long long*)(ws + 34 * 1048576);  // 8 MB bitmask

  float* outO  = (float*)d_out;                      // [B,S,D]   4M fp32
  float* attnW = outO + 4 * 1048576;                 // [B,H,S,S] 64M fp32

  mask_probe<<<1, 256, 0, stream>>>(mask, mfl);
  prep<<<11264, 256, 0, stream>>>(query, key, value, Xbf, Wq, Wk, Wv, Wo, wt,
                                  mask, mfl, PM);
  gemm_qkv<<<dim3(32, 8, 3), 256, 0, stream>>>(Xbf, wt, bq, bk, bv,
                                               (void*)Qws, (void*)Kws, (void*)Vtws);
  attn_kernel<<<dim3(16, 64), 512, 0, stream>>>(Qws, Kws, Vtws, PM, attnW, AOws);
  gemm_out<<<dim3(32, 8), 256, 0, stream>>>(AOws, wt + 3 * 1048576, bo, outO);
}